// Round 3
// baseline (60.681 us; speedup 1.0000x reference)
//
#include <hip/hip_runtime.h>

// Problem constants (fixed by the reference).
#define BSZ    16      // batch
#define NN     1024    // tokens per batch
#define DIN    512     // input dim
#define KD     256     // NUM_CAPS * DIM_CAPS
#define NCAPS  16
#define EPS    1e-7f

#define ROWS_PER_BLK 32
#define NCHUNK (NN / ROWS_PER_BLK)   // 32 chunks per batch

// ---------------------------------------------------------------------------
// Single fused kernel. grid = BSZ*NCHUNK = 512 blocks, 1024 threads.
//
// Phase A (all blocks): column-sum this block's 32 input rows -> P[blk][512].
// Release: __syncthreads() drains every wave's stores (compiler emits full
// s_waitcnt before s_barrier), then t0 does __threadfence() (buffer_wbl2,
// device scope -- the whole block's stores are in this XCD's L2) and
// atomicAdd(cnt[b]). The block seeing old==NCHUNK-1 is the unique "last"
// block for batch b and runs the tail; others exit. No spinning -> no
// co-residency assumption, dispatch-order independent.
//
// Tail (last block per batch): acquire __threadfence() (buffer_inv -- also
// evicts stale P lines cached in this XCD's L2 from the previous graph
// replay), then:
//   1) xs[i]  = sum of 32 P rows           (2 groups x 16 rows, LDS reduce)
//   2) H[d]   = sum_i xs[i]*W[i][d]        (4 i-groups x 128, LDS reduce)
//   3) squash + write 16 identical k-copies (exact routing degeneracy:
//      b=0 -> softmax = 1/16 exactly; agreement update is k-constant).
// ---------------------------------------------------------------------------
__global__ __launch_bounds__(1024, 8) void caps_fused(
    const float* __restrict__ in, const float* __restrict__ W,
    float* __restrict__ P, unsigned* __restrict__ cnt,
    float* __restrict__ out)
{
    __shared__ float4 shA[8][128];     // 16 KB  (phase A reduce)
    __shared__ float  part[2][DIN];    //  4 KB  (tail phase 1)
    __shared__ float  xs[DIN];         //  2 KB
    __shared__ float  red2[4][KD];     //  4 KB  (tail phase 2)
    __shared__ float  svs[KD];         //  1 KB
    __shared__ float  red[KD];         //  1 KB  (sum-of-squares tree)
    __shared__ int    sh_last;

    const int blk = blockIdx.x;
    const int b   = blk >> 5;          // / NCHUNK
    const int t   = threadIdx.x;

    // ---- Phase A: 32 rows x 128 float4. Per iter the block reads 8 whole
    // rows (16 KB contiguous); 16 B/lane fully coalesced.
    {
        const int col4 = t & 127;
        const int rg   = t >> 7;       // 0..7
        const float4* base = (const float4*)in
            + (size_t)blk * ROWS_PER_BLK * (DIN / 4);
        float4 acc = make_float4(0.f, 0.f, 0.f, 0.f);
        #pragma unroll
        for (int j = 0; j < 4; ++j) {
            float4 v = base[(size_t)(rg + 8 * j) * (DIN / 4) + col4];
            acc.x += v.x; acc.y += v.y; acc.z += v.z; acc.w += v.w;
        }
        shA[rg][col4] = acc;
    }
    __syncthreads();
    if (t < 128) {
        float4 a = shA[0][t];
        #pragma unroll
        for (int g = 1; g < 8; ++g) {
            float4 v = shA[g][t];
            a.x += v.x; a.y += v.y; a.z += v.z; a.w += v.w;
        }
        ((float4*)P)[(size_t)blk * (DIN / 4) + t] = a;
    }
    __syncthreads();                   // all waves' P stores drained (vmcnt 0)

    if (t == 0) {
        __threadfence();               // release: write-back L2 device-wide
        unsigned old = atomicAdd(&cnt[b], 1u);
        sh_last = (old == NCHUNK - 1);
    }
    __syncthreads();
    if (!sh_last) return;

    // ---- Tail: this is the unique last block of batch b.
    __threadfence();                   // acquire: invalidate L1/L2
    __syncthreads();

    // Phase 1: xs[i] = sum over 32 partial rows (fixed order: 16 + 16).
    {
        const int i = t & 511;
        const int g = t >> 9;          // 0 or 1
        const float* p = P + ((size_t)b * NCHUNK + g * 16) * DIN + i;
        float a = 0.f;
        #pragma unroll
        for (int j = 0; j < 16; ++j) a += p[(size_t)j * DIN];
        part[g][i] = a;
    }
    __syncthreads();
    if (t < DIN) xs[t] = part[0][t] + part[1][t];
    __syncthreads();

    // Phase 2: H[d] = sum_i xs[i] * W[i][d], i split 4 x 128.
    // xs is an LDS broadcast; W loads coalesced (64 lanes x 4 B = 256 B).
    {
        const int d = t & 255;
        const int h = t >> 8;          // 0..3
        const float* w = W + (size_t)(h * 128) * KD + d;
        float acc = 0.f;
        #pragma unroll 8
        for (int ii = 0; ii < 128; ++ii)
            acc += xs[h * 128 + ii] * w[(size_t)ii * KD];
        red2[h][d] = acc;
    }
    __syncthreads();
    if (t < KD) {
        float sv = (red2[0][t] + red2[1][t] + red2[2][t] + red2[3][t])
                   * (1.0f / 16.0f);   // softmax c = 1/16 exactly
        svs[t] = sv;
        red[t] = sv * sv;
    }
    __syncthreads();
    for (int off = 128; off > 0; off >>= 1) {
        if (t < off) red[t] += red[t + off];
        __syncthreads();
    }
    const float sq    = red[0];
    const float scale = (sq / (1.0f + sq)) / sqrtf(sq + EPS);

    // Phase 3: write 16 identical k-copies; 4 stores per thread, coalesced.
    {
        const int d  = t & 255;
        const int kk = t >> 8;         // 0..3
        const float o = scale * svs[d];
        #pragma unroll
        for (int m = 0; m < 4; ++m)
            out[((size_t)b * NCAPS + (kk * 4 + m)) * KD + d] = o;
    }
}

extern "C" void kernel_launch(void* const* d_in, const int* in_sizes, int n_in,
                              void* d_out, int out_size, void* d_ws, size_t ws_size,
                              hipStream_t stream)
{
    const float* in = (const float*)d_in[0];  // [16,1024,512] f32
    const float* W  = (const float*)d_in[1];  // [512,256] f32
    float* out = (float*)d_out;               // [16,16,256] f32

    float*    P   = (float*)d_ws;                          // 512*512 f32 = 1 MB
    unsigned* cnt = (unsigned*)(P + (size_t)BSZ * NCHUNK * DIN); // 16 u32

    // Counters must be zero at kernel start on EVERY replay (ws is poisoned
    // once, never re-poisoned); this memset is captured into the graph.
    hipMemsetAsync(cnt, 0, BSZ * sizeof(unsigned), stream);

    caps_fused<<<BSZ * NCHUNK, 1024, 0, stream>>>(in, W, P, cnt, out);
}

// Round 4
// 19.433 us; speedup vs baseline: 3.1225x; 3.1225x over previous
//
#include <hip/hip_runtime.h>

// Problem constants (fixed by the reference).
#define BSZ    16      // batch
#define NN     1024    // tokens per batch
#define DIN    512     // input dim
#define KD     256     // NUM_CAPS * DIM_CAPS
#define NCAPS  16
#define EPS    1e-7f

#define ROWS_PER_BLK 32
#define NCHUNK (NN / ROWS_PER_BLK)   // 32 partial rows per batch

// ---------------------------------------------------------------------------
// Kernel A (unchanged from the 15.4 µs version): partial column sums.
// grid = 512 blocks, 256 threads. Each block reads 32 rows (64 KB contiguous,
// float4 coalesced) and emits one partial row: P[blk][i].
// Cross-kernel visibility of P is handled by the runtime's kernel-boundary
// cache ops -- NO explicit device fences (R3 showed 512 per-block
// __threadfence()'s serialize at L2 and cost 45 µs).
// ---------------------------------------------------------------------------
__global__ __launch_bounds__(256) void colsum_partial(
    const float* __restrict__ in, float* __restrict__ P)
{
    __shared__ float4 sh[128];
    int blk = blockIdx.x;
    int t   = threadIdx.x;
    int par  = t >> 7;      // 0 or 1
    int col4 = t & 127;     // float4 column index

    const float4* base = (const float4*)in
        + (size_t)blk * ROWS_PER_BLK * (DIN / 4);

    float4 acc = make_float4(0.f, 0.f, 0.f, 0.f);
    #pragma unroll
    for (int r = 0; r < ROWS_PER_BLK / 2; ++r) {
        float4 v = base[(size_t)(2 * r + par) * (DIN / 4) + col4];
        acc.x += v.x; acc.y += v.y; acc.z += v.z; acc.w += v.w;
    }
    if (par) sh[col4] = acc;
    __syncthreads();
    if (!par) {
        float4 o = sh[col4];
        acc.x += o.x; acc.y += o.y; acc.z += o.z; acc.w += o.w;
        ((float4*)P)[(size_t)blk * (DIN / 4) + col4] = acc;
    }
}

// ---------------------------------------------------------------------------
// Kernel BC (fused tail; numerics identical to the R3 tail that validated):
// grid = BSZ = 16 blocks, 1024 threads.
//   1) xs[i] = sum of 32 P rows   (2 groups x 16 rows, fixed order)
//   2) H[d]  = sum_i xs[i]*W[i][d]  (4 i-groups x 128, LDS reduce;
//      xs is an LDS broadcast, W coalesced across lanes, unroll 8 gives
//      8 outstanding loads to hide L2 latency)
//   3) squash + 16 identical k-copies (exact routing degeneracy: b=0 ->
//      softmax = 1/16 exactly; agreement update is k-constant).
// ---------------------------------------------------------------------------
__global__ __launch_bounds__(1024) void gemm_squash(
    const float* __restrict__ P, const float* __restrict__ W,
    float* __restrict__ out)
{
    __shared__ float part[2][DIN];     // 4 KB
    __shared__ float xs[DIN];          // 2 KB
    __shared__ float red2[4][KD];      // 4 KB
    __shared__ float svs[KD];          // 1 KB
    __shared__ float red[KD];          // 1 KB

    const int b = blockIdx.x;
    const int t = threadIdx.x;

    // Phase 1: xs[i] = sum over 32 partial rows (fixed order 16+16).
    {
        const int i = t & 511;
        const int g = t >> 9;          // 0 or 1
        const float* p = P + ((size_t)b * NCHUNK + g * 16) * DIN + i;
        float a = 0.f;
        #pragma unroll
        for (int j = 0; j < 16; ++j) a += p[(size_t)j * DIN];
        part[g][i] = a;
    }
    __syncthreads();
    if (t < DIN) xs[t] = part[0][t] + part[1][t];
    __syncthreads();

    // Phase 2: H[d] = sum_i xs[i] * W[i][d], i split 4 x 128.
    {
        const int d = t & 255;
        const int h = t >> 8;          // 0..3
        const float* w = W + (size_t)(h * 128) * KD + d;
        float acc = 0.f;
        #pragma unroll 8
        for (int ii = 0; ii < 128; ++ii)
            acc += xs[h * 128 + ii] * w[(size_t)ii * KD];
        red2[h][d] = acc;
    }
    __syncthreads();
    if (t < KD) {
        float sv = (red2[0][t] + red2[1][t] + red2[2][t] + red2[3][t])
                   * (1.0f / 16.0f);   // softmax c = 1/16 exactly
        svs[t] = sv;
        red[t] = sv * sv;
    }
    __syncthreads();
    for (int off = 128; off > 0; off >>= 1) {
        if (t < off) red[t] += red[t + off];
        __syncthreads();
    }
    const float sq    = red[0];
    const float scale = (sq / (1.0f + sq)) / sqrtf(sq + EPS);

    // Phase 3: 16 identical k-copies; 4 coalesced stores per thread.
    {
        const int d  = t & 255;
        const int kk = t >> 8;         // 0..3
        const float o = scale * svs[d];
        #pragma unroll
        for (int m = 0; m < 4; ++m)
            out[((size_t)b * NCAPS + (kk * 4 + m)) * KD + d] = o;
    }
}

extern "C" void kernel_launch(void* const* d_in, const int* in_sizes, int n_in,
                              void* d_out, int out_size, void* d_ws, size_t ws_size,
                              hipStream_t stream)
{
    const float* in = (const float*)d_in[0];  // [16,1024,512] f32
    const float* W  = (const float*)d_in[1];  // [512,256] f32
    float* out = (float*)d_out;               // [16,16,256] f32

    float* P = (float*)d_ws;                  // 512*512 f32 = 1 MB

    colsum_partial<<<BSZ * NCHUNK, 256, 0, stream>>>(in, P);
    gemm_squash<<<BSZ, 1024, 0, stream>>>(P, W, out);
}

// Round 5
// 15.266 us; speedup vs baseline: 3.9748x; 1.2730x over previous
//
#include <hip/hip_runtime.h>

// Problem constants (fixed by the reference).
#define BSZ    16      // batch
#define NN     1024    // tokens per batch
#define DIN    512     // input dim
#define KD     256     // NUM_CAPS * DIM_CAPS
#define NCAPS  16
#define EPS    1e-7f

#define ROWS_PER_BLK 32
#define NCHUNK (NN / ROWS_PER_BLK)   // 32 partial rows per batch
#define NSPLIT 16                    // i-splits for the tiny GEMM
#define ICHUNK (DIN / NSPLIT)        // 32

// ---------------------------------------------------------------------------
// Kernel A (proven): partial column sums. grid = 512 blocks, 256 threads.
// Each block reads 32 rows (64 KB contiguous, float4 coalesced, 16 loads in
// flight per thread) and emits one partial row P[blk][512].
// ---------------------------------------------------------------------------
__global__ __launch_bounds__(256) void colsum_partial(
    const float* __restrict__ in, float* __restrict__ P)
{
    __shared__ float4 sh[128];
    int blk = blockIdx.x;
    int t   = threadIdx.x;
    int par  = t >> 7;      // 0 or 1
    int col4 = t & 127;     // float4 column index

    const float4* base = (const float4*)in
        + (size_t)blk * ROWS_PER_BLK * (DIN / 4);

    float4 acc = make_float4(0.f, 0.f, 0.f, 0.f);
    #pragma unroll
    for (int r = 0; r < ROWS_PER_BLK / 2; ++r) {
        float4 v = base[(size_t)(2 * r + par) * (DIN / 4) + col4];
        acc.x += v.x; acc.y += v.y; acc.z += v.z; acc.w += v.w;
    }
    if (par) sh[col4] = acc;
    __syncthreads();
    if (!par) {
        float4 o = sh[col4];
        acc.x += o.x; acc.y += o.y; acc.z += o.z; acc.w += o.w;
        ((float4*)P)[(size_t)blk * (DIN / 4) + col4] = acc;
    }
}

// ---------------------------------------------------------------------------
// Kernel B: partial tiny-GEMM, 256 blocks (b,s), 256 threads.
// ALL global reads are single-round independent float4 loads (fixes the R4
// latency-chain: VGPR-starved strided scalar loads serialized at ~900 cyc).
//   stage: 8x float4 of W rows [i0,i0+32) -> wl (32 KB)  [8 loads in flight]
//          1x float4 of this block's P tile -> pt        [1 load in flight]
//   reduce pt over c (8 groups of 4, then 8) -> xs[32]
//   dot from LDS: acc[d] = sum_i xs[i] * wl[i][d]  (2-way bank alias = free)
// ---------------------------------------------------------------------------
__global__ __launch_bounds__(256) void partial_gemm(
    const float* __restrict__ P, const float* __restrict__ W,
    float* __restrict__ P2)
{
    __shared__ float wl[ICHUNK][KD];   // 32 KB
    __shared__ float pt[ICHUNK][33];   // P tile, padded (col-sum over rows)
    __shared__ float pr[8][33];        // group partials
    __shared__ float xs[ICHUNK];

    const int b  = blockIdx.x >> 4;
    const int s  = blockIdx.x & (NSPLIT - 1);
    const int t  = threadIdx.x;
    const int i0 = s * ICHUNK;

    // Issue ALL global loads first (9 independent float4 loads per thread).
    const float4* W4 = (const float4*)W + (size_t)i0 * (KD / 4);
    float4 wv[8];
    #pragma unroll
    for (int k = 0; k < 8; ++k)
        wv[k] = W4[k * 256 + t];               // 2048 float4 = 32 rows x 64

    const int c = t >> 3;                      // P row 0..31
    const int q = t & 7;                       // float4 col within chunk
    float4 pv = ((const float4*)P)[((size_t)b * NCHUNK + c) * (DIN / 4)
                                   + (i0 / 4) + q];

    // LDS writes (wait on the loads, all in one round).
    #pragma unroll
    for (int k = 0; k < 8; ++k) {
        int idx  = k * 256 + t;
        int row  = idx >> 6;                   // 0..31
        int col4 = idx & 63;
        *(float4*)&wl[row][col4 * 4] = wv[k];  // contiguous b128, no conflict
    }
    pt[c][q * 4 + 0] = pv.x;
    pt[c][q * 4 + 1] = pv.y;
    pt[c][q * 4 + 2] = pv.z;
    pt[c][q * 4 + 3] = pv.w;
    __syncthreads();

    // Column-sum pt over c: 8 groups x 4 rows, then 8.
    {
        const int g = t >> 5;                  // 0..7
        const int i = t & 31;
        pr[g][i] = pt[g * 4 + 0][i] + pt[g * 4 + 1][i]
                 + pt[g * 4 + 2][i] + pt[g * 4 + 3][i];
    }
    __syncthreads();
    if (t < ICHUNK)
        xs[t] = pr[0][t] + pr[1][t] + pr[2][t] + pr[3][t]
              + pr[4][t] + pr[5][t] + pr[6][t] + pr[7][t];
    __syncthreads();

    // 32-deep dot entirely from LDS.
    float acc = 0.f;
    #pragma unroll
    for (int i = 0; i < ICHUNK; ++i)
        acc += xs[i] * wl[i][t];
    P2[((size_t)b * NSPLIT + s) * KD + t] = acc;
}

// ---------------------------------------------------------------------------
// Kernel C: reduce NSPLIT partials, squash, write 16 identical k-copies.
// grid = 16 blocks, 256 threads. P2 tile (16 KB) staged in ONE float4 round
// (4 independent loads/thread), reduced via LDS.
// ---------------------------------------------------------------------------
__global__ __launch_bounds__(256) void squash_out(
    const float* __restrict__ P2, float* __restrict__ out)
{
    __shared__ float part[4][KD];
    __shared__ float svs[KD];
    __shared__ float red[KD];

    const int b = blockIdx.x;
    const int t = threadIdx.x;
    const int g  = t >> 6;                     // 0..3
    const int d4 = t & 63;                     // float4 col 0..63

    const float4* P24 = (const float4*)P2 + (size_t)b * NSPLIT * (KD / 4);
    float4 a = make_float4(0.f, 0.f, 0.f, 0.f);
    #pragma unroll
    for (int j = 0; j < 4; ++j) {              // 4 independent loads
        float4 v = P24[(size_t)(g * 4 + j) * (KD / 4) + d4];
        a.x += v.x; a.y += v.y; a.z += v.z; a.w += v.w;
    }
    *(float4*)&part[g][d4 * 4] = a;
    __syncthreads();

    const float sv = (part[0][t] + part[1][t] + part[2][t] + part[3][t])
                     * (1.0f / 16.0f);         // softmax c = 1/16 exactly
    svs[t] = sv;
    red[t] = sv * sv;
    __syncthreads();
    for (int off = 128; off > 0; off >>= 1) {
        if (t < off) red[t] += red[t + off];
        __syncthreads();
    }
    const float sq    = red[0];
    const float scale = (sq / (1.0f + sq)) / sqrtf(sq + EPS);
    const float o     = scale * svs[t];

    #pragma unroll
    for (int k = 0; k < NCAPS; ++k)
        out[((size_t)b * NCAPS + k) * KD + t] = o;
}

extern "C" void kernel_launch(void* const* d_in, const int* in_sizes, int n_in,
                              void* d_out, int out_size, void* d_ws, size_t ws_size,
                              hipStream_t stream)
{
    const float* in = (const float*)d_in[0];  // [16,1024,512] f32
    const float* W  = (const float*)d_in[1];  // [512,256] f32
    float* out = (float*)d_out;               // [16,16,256] f32

    float* P  = (float*)d_ws;                       // 512*512 f32 = 1 MB
    float* P2 = P + (size_t)BSZ * NCHUNK * DIN;     // 16*16*256 f32 = 256 KB

    colsum_partial<<<BSZ * NCHUNK, 256, 0, stream>>>(in, P);
    partial_gemm<<<BSZ * NSPLIT, 256, 0, stream>>>(P, W, P2);
    squash_out<<<BSZ, 256, 0, stream>>>(P2, out);
}